// Round 9
// baseline (281.406 us; speedup 1.0000x reference)
//
#include <hip/hip_runtime.h>
#include <hip/hip_bf16.h>
#include <math.h>

#define BB 64
#define NN 76
#define TT 128
#define DD 128
#define AH 8
#define NHEADS 4
#define DFF 512
#define FAH 128
#define DK 32
#define BN (BB*NN)        // 4864
#define ROWS 8
#define NBLK (BN/ROWS)    // 608
#define K1GRID 1216       // 4 tiles/block, stride K1GRID: 4*1216 = 4864 exactly

// LDS-only barrier: waits ds ops (lgkmcnt) but leaves global register loads
// (vmcnt) in flight across the barrier. Avoids hipcc's __syncthreads lowering
// (s_waitcnt vmcnt(0) lgkmcnt(0)) which drains the in-flight tile stream.
__device__ __forceinline__ void bar_lds() {
    asm volatile("s_waitcnt lgkmcnt(0)" ::: "memory");
    __builtin_amdgcn_s_barrier();
    __builtin_amdgcn_sched_barrier(0);
}

// ---------------- K1: missing-aware temporal attention ----------------
// Persistent-lite: 1216 blocks x 512 thr, each block owns exactly 4 tiles
// (bid, bid+1216, bid+2432, bid+3648) -- fully unrolled STRAIGHT-LINE
// schedule with register double-buffer:
//   issue(A,T0); issue(B,T1); compute(A); issue(A,T2); compute(B);
//   issue(B,T3); compute(A); compute(B)
// All issues are unconditional and the code is branch-free at the schedule
// level, so every vmcnt count is a compile-time constant: compute(i) waits
// vmcnt(8)-style counted waits while tile i+1's 8 loads stay in flight
// across all bar_lds barriers -> the per-CU HBM stream never drains.
// Weights live in LDS (frees 16 VGPR); h double-buffer = 64 VGPR.
__global__ __launch_bounds__(512, 6) void k1_temporal(
    const float* __restrict__ H, const float* __restrict__ mask,
    const float* __restrict__ Wt, const float* __restrict__ Wx,
    const float* __restrict__ rate, const float* __restrict__ obs_bias,
    const float* __restrict__ miss_bias, float* __restrict__ emb)
{
    __shared__ __align__(16) float wtx[2*DD*AH];    // 8 KB: Wt then Wx
    __shared__ __align__(16) float wqs[DD];
    __shared__ __align__(16) float dots[TT];
    __shared__ __align__(16) float as_[TT];
    __shared__ __align__(16) float parts[16][DD];   // 8 KB
    __shared__ float qpart[2][AH];
    __shared__ float redsum[2];

    const int tid = threadIdx.x;
    const int lane = tid & 63, w = tid >> 6;
    const int c = tid & 31, g = tid >> 5;

    // one-time: stage Wt/Wx to LDS (1 float4/thread)
    const float* wsrc = (tid < 256) ? (Wt + 4*tid) : (Wx + 4*(tid-256));
    const float4 wld = *(const float4*)wsrc;
    const float sr   = 1.f / (1.f + expf(-rate[0]));
    const float obsv = obs_bias[0], missv = miss_bias[0];
    *(float4*)&wtx[4*tid] = wld;

    auto issue = [&](float4 (&h)[8], float& r127, float& maskv, int t) {
        const size_t base = (size_t)t * (TT*DD);
        if (tid < DD) {
            r127  = H[base + (TT-1)*DD + tid];
            maskv = mask[(size_t)t*TT + tid];
        }
        const float4* Hg4 = (const float4*)(H + base);
        #pragma unroll
        for (int j = 0; j < 8; ++j) h[j] = Hg4[j*512 + tid];
    };

    auto compute = [&](const float4 (&h)[8], float r127, float maskv, int t) {
        // q[a] = row127 . Wt[:,a]  (waves 0-1; Wt row from LDS)
        if (tid < DD) {
            float p[AH];
            #pragma unroll
            for (int a = 0; a < AH; ++a) p[a] = r127 * wtx[tid*AH + a];
            #pragma unroll
            for (int a = 0; a < AH; ++a) {
                float v = p[a];
                #pragma unroll
                for (int m = 1; m < 64; m <<= 1) v += __shfl_xor(v, m, 64);
                if (lane == 0) qpart[w][a] = v;
            }
        }
        bar_lds();
        // wq[d] = sum_a q[a]*Wx[d,a]
        if (tid < DD) {
            float acc = 0.f;
            #pragma unroll
            for (int a = 0; a < AH; ++a)
                acc += (qpart[0][a] + qpart[1][a]) * wtx[DD*AH + tid*AH + a];
            wqs[tid] = acc;
        }
        bar_lds();

        // dot[t] = H[t].wq ; rows t = g + 16j; 32-lane group reduce
        const float4 wq4 = *(const float4*)&wqs[4*c];
        #pragma unroll
        for (int j = 0; j < 8; ++j) {
            float p = h[j].x*wq4.x + h[j].y*wq4.y + h[j].z*wq4.z + h[j].w*wq4.w;
            #pragma unroll
            for (int m = 1; m < 32; m <<= 1) p += __shfl_xor(p, m, 64);
            if (c == 0) dots[g + 16*j] = p;
        }
        bar_lds();

        // e[t] + UNNORMALIZED exp (e bounded ~2.6 -> no max subtraction);
        // 1/sum folded into the emb store.
        if (tid < TT) {
            const float dot = dots[tid];
            const float sig = 1.f / (1.f + expf(-dot));
            const float bt  = (float)(TT - tid);
            const float denom = sr * (logf(2.72f + (1.f - sig)) * bt);
            float e = fmaxf(sig / denom, 0.f);
            e += (maskv > 0.5f) ? obsv : missv;
            const float ex = expf(e);
            as_[tid] = ex;
            float vs = ex;
            #pragma unroll
            for (int m = 1; m < 64; m <<= 1) vs += __shfl_xor(vs, m, 64);
            if (lane == 0) redsum[w] = vs;
        }
        bar_lds();
        const float inv = 1.f / (redsum[0] + redsum[1]);

        // emb[d] = inv * sum_t ex[t]*H[t,d]
        float4 facc = make_float4(0.f, 0.f, 0.f, 0.f);
        #pragma unroll
        for (int j = 0; j < 8; ++j) {
            const float a = as_[g + 16*j];
            facc.x += a*h[j].x; facc.y += a*h[j].y;
            facc.z += a*h[j].z; facc.w += a*h[j].w;
        }
        *(float4*)&parts[g][4*c] = facc;
        bar_lds();
        if (tid < DD) {
            float acc = 0.f;
            #pragma unroll
            for (int gg = 0; gg < 16; ++gg) acc += parts[gg][tid];
            emb[(size_t)t*DD + tid] = acc * inv;
        }
        bar_lds();   // parts reused next tile; protect with LDS-only barrier
    };

    const int bid = blockIdx.x;
    float4 hA[8], hB[8];
    float rA = 0.f, rB = 0.f, mA = 0.f, mB = 0.f;

    // straight-line, branch-free schedule: counts are static everywhere
    issue(hA, rA, mA, bid);
    issue(hB, rB, mB, bid + K1GRID);
    compute(hA, rA, mA, bid);
    issue(hA, rA, mA, bid + 2*K1GRID);
    compute(hB, rB, mB, bid + K1GRID);
    issue(hB, rB, mB, bid + 3*K1GRID);
    compute(hA, rA, mA, bid + 2*K1GRID);
    compute(hB, rB, mB, bid + 3*K1GRID);
}

// ---------------- K2a: LN1 + Q/K/V projections ----------------
__global__ __launch_bounds__(256) void k2a_ln_qkv(
    const float* __restrict__ emb,
    const float* __restrict__ ln_a, const float* __restrict__ ln_b,
    const float* __restrict__ Wq, const float* __restrict__ bq,
    const float* __restrict__ Wk, const float* __restrict__ bk,
    const float* __restrict__ Wv, const float* __restrict__ bv,
    float* __restrict__ qb, float* __restrict__ kb, float* __restrict__ vb)
{
    __shared__ float xs[ROWS][DD];
    const int tid = threadIdx.x;
    const int r0 = blockIdx.x * ROWS;

    for (int i = tid; i < ROWS*DD; i += 256) {
        const int r = i / DD, d = i % DD;
        xs[r][d] = emb[(size_t)(r0+r)*DD + d];
    }
    __syncthreads();

    {   // LayerNorm (ddof=1, eps added to std); wave w -> rows 2w,2w+1
        const int wv_ = tid >> 6, lane = tid & 63;
        for (int rr = 0; rr < 2; ++rr) {
            const int r = wv_*2 + rr;
            const float x0 = xs[r][lane], x1 = xs[r][lane+64];
            float s = x0 + x1;
            #pragma unroll
            for (int m = 1; m < 64; m <<= 1) s += __shfl_xor(s, m, 64);
            const float mean = s / (float)DD;
            const float d0 = x0 - mean, d1 = x1 - mean;
            float v = d0*d0 + d1*d1;
            #pragma unroll
            for (int m = 1; m < 64; m <<= 1) v += __shfl_xor(v, m, 64);
            const float inv = 1.f / (sqrtf(v / (float)(DD-1)) + 1e-7f);
            xs[r][lane]    = ln_a[lane]   * (d0*inv) + ln_b[lane];
            xs[r][lane+64] = ln_a[lane+64]* (d1*inv) + ln_b[lane+64];
        }
    }
    __syncthreads();

    const int j = tid & 127, half = tid >> 7, rbase = half*4;
    float aq[4] = {0,0,0,0}, ak[4] = {0,0,0,0}, av[4] = {0,0,0,0};
    for (int d = 0; d < DD; ++d) {
        const float wqv = Wq[d*DD+j], wkv = Wk[d*DD+j], wvv = Wv[d*DD+j];
        #pragma unroll
        for (int r = 0; r < 4; ++r) {
            const float xv = xs[rbase+r][d];
            aq[r] += xv*wqv; ak[r] += xv*wkv; av[r] += xv*wvv;
        }
    }
    const float bqv = bq[j], bkv = bk[j], bvv = bv[j];
    #pragma unroll
    for (int r = 0; r < 4; ++r) {
        const size_t o = (size_t)(r0 + rbase + r)*DD + j;
        qb[o] = aq[r]+bqv; kb[o] = ak[r]+bkv; vb[o] = av[r]+bvv;
    }
}

// ---------------- K2b: per-(b,head) self-attention over N ----------------
__global__ __launch_bounds__(128) void k2b_attn(
    const float* __restrict__ qb, const float* __restrict__ kb,
    const float* __restrict__ vb, float* __restrict__ ctx)
{
    __shared__ float Qs[NN][DK], Ks[NN][DK], Vs[NN][DK];
    __shared__ float Ps[NN][NN+1];   // stride 77: bank-conflict-free
    const int b = blockIdx.x / NHEADS, h = blockIdx.x % NHEADS;
    const int tid = threadIdx.x;
    const int co = h*DK;

    for (int i = tid; i < NN*DK; i += 128) {
        const int r = i / DK, c = i % DK;
        const size_t o = (size_t)(b*NN + r)*DD + co + c;
        Qs[r][c] = qb[o]; Ks[r][c] = kb[o]; Vs[r][c] = vb[o];
    }
    __syncthreads();

    const float scale = 0.17677669529663687f;   // 1/sqrt(32)
    if (tid < NN) {
        float qr[DK];
        #pragma unroll
        for (int c = 0; c < DK; ++c) qr[c] = Qs[tid][c];
        float mx = -1e30f;
        for (int k = 0; k < NN; ++k) {
            float s = 0.f;
            #pragma unroll
            for (int c = 0; c < DK; ++c) s += qr[c]*Ks[k][c];
            s *= scale;
            Ps[tid][k] = s;
            mx = fmaxf(mx, s);
        }
        float sum = 0.f;
        for (int k = 0; k < NN; ++k) { const float e = expf(Ps[tid][k]-mx); Ps[tid][k] = e; sum += e; }
        const float inv = 1.f/sum;
        float acc[DK];
        #pragma unroll
        for (int c = 0; c < DK; ++c) acc[c] = 0.f;
        for (int k = 0; k < NN; ++k) {
            const float p = Ps[tid][k];
            #pragma unroll
            for (int c = 0; c < DK; ++c) acc[c] += p*Vs[k][c];
        }
        const size_t o = (size_t)(b*NN + tid)*DD + co;
        #pragma unroll
        for (int c = 0; c < DK; ++c) ctx[o+c] = acc[c]*inv;
    }
}

// ---------------- K23: Wo projection + residual + LN2 + FFN + residual ----
__global__ __launch_bounds__(256) void k23_proj_ffn(
    const float* __restrict__ ctx, const float* __restrict__ emb,
    const float* __restrict__ Wo, const float* __restrict__ bo,
    const float* __restrict__ ln_a, const float* __restrict__ ln_b,
    const float* __restrict__ w1, const float* __restrict__ b1,
    const float* __restrict__ w2, const float* __restrict__ b2,
    float* __restrict__ mha, float* __restrict__ x2)
{
    __shared__ float cs[ROWS][DD];        // ctx rows
    __shared__ float xs[ROWS][DD];        // x = emb + mha
    __shared__ float x1s[ROWS][DD];       // LN2(x)
    __shared__ float hs[ROWS][DFF];       // 16 KB
    __shared__ float parts[2][ROWS][DD];  // 8 KB
    const int tid = threadIdx.x;
    const int r0 = blockIdx.x * ROWS;

    for (int i = tid; i < ROWS*DD; i += 256) {
        const int r = i / DD, d = i % DD;
        cs[r][d] = ctx[(size_t)(r0+r)*DD + d];
    }
    __syncthreads();

    {   // mha = ctx @ Wo + bo ; x = emb + mha (LDS); mha -> global
        const int j = tid & 127, half = tid >> 7, rbase = half*4;
        float acc[4] = {0,0,0,0};
        for (int d = 0; d < DD; ++d) {
            const float wv = Wo[d*DD+j];
            #pragma unroll
            for (int r = 0; r < 4; ++r) acc[r] += cs[rbase+r][d]*wv;
        }
        const float bov = bo[j];
        #pragma unroll
        for (int r = 0; r < 4; ++r) {
            const size_t o = (size_t)(r0+rbase+r)*DD + j;
            const float m = acc[r] + bov;
            mha[o] = m;
            xs[rbase+r][j] = emb[o] + m;
        }
    }
    __syncthreads();

    {   // LN2
        const int wv_ = tid >> 6, lane = tid & 63;
        for (int rr = 0; rr < 2; ++rr) {
            const int r = wv_*2 + rr;
            const float v0 = xs[r][lane], v1 = xs[r][lane+64];
            float s = v0 + v1;
            #pragma unroll
            for (int m = 1; m < 64; m <<= 1) s += __shfl_xor(s, m, 64);
            const float mean = s / (float)DD;
            const float d0 = v0-mean, d1 = v1-mean;
            float vv = d0*d0 + d1*d1;
            #pragma unroll
            for (int m = 1; m < 64; m <<= 1) vv += __shfl_xor(vv, m, 64);
            const float inv = 1.f / (sqrtf(vv/(float)(DD-1)) + 1e-7f);
            x1s[r][lane]    = ln_a[lane]   * (d0*inv) + ln_b[lane];
            x1s[r][lane+64] = ln_a[lane+64]* (d1*inv) + ln_b[lane+64];
        }
    }
    __syncthreads();

    {   // h = relu(x1 @ w1 + b1) ; thread -> cols tid, tid+256
        float acc0[ROWS], acc1[ROWS];
        #pragma unroll
        for (int r = 0; r < ROWS; ++r) { acc0[r]=0.f; acc1[r]=0.f; }
        for (int d = 0; d < DD; ++d) {
            const float wv0 = w1[d*DFF + tid], wv1 = w1[d*DFF + tid + 256];
            #pragma unroll
            for (int r = 0; r < ROWS; ++r) {
                const float xv = x1s[r][d];
                acc0[r] += xv*wv0; acc1[r] += xv*wv1;
            }
        }
        const float b10 = b1[tid], b11 = b1[tid+256];
        #pragma unroll
        for (int r = 0; r < ROWS; ++r) {
            hs[r][tid]     = fmaxf(acc0[r]+b10, 0.f);
            hs[r][tid+256] = fmaxf(acc1[r]+b11, 0.f);
        }
    }
    __syncthreads();

    {   // ffn = h @ w2 + b2 ; x2 = x + ffn
        const int j = tid & 127, half = tid >> 7;
        float acc[ROWS];
        #pragma unroll
        for (int r = 0; r < ROWS; ++r) acc[r] = 0.f;
        for (int k = half*256; k < half*256 + 256; ++k) {
            const float wv = w2[k*DD + j];
            #pragma unroll
            for (int r = 0; r < ROWS; ++r) acc[r] += hs[r][k]*wv;
        }
        #pragma unroll
        for (int r = 0; r < ROWS; ++r) parts[half][r][j] = acc[r];
        __syncthreads();
        if (half == 0) {
            const float b2v = b2[j];
            #pragma unroll
            for (int r = 0; r < ROWS; ++r) {
                const size_t o = (size_t)(r0+r)*DD + j;
                x2[o] = xs[r][j] + parts[0][r][j] + parts[1][r][j] + b2v;
            }
        }
    }
}

// ---------------- K-decov: DeCov partials per (n, d-chunk) ----------------
__global__ __launch_bounds__(256) void k_decov(
    const float* __restrict__ mha, float* __restrict__ partial)
{
    __shared__ float Cs[BB][DD];     // 32 KB
    __shared__ float means[DD];
    __shared__ float reda[256];
    __shared__ float redb[256];
    const int n = blockIdx.x, dc = blockIdx.y;
    const int tid = threadIdx.x;
    for (int i = tid; i < BB*DD; i += 256) {
        const int bb = i / DD, d = i % DD;
        Cs[bb][d] = mha[((size_t)bb*NN + n)*DD + d];
    }
    __syncthreads();
    if (tid < DD) {
        float s = 0.f;
        for (int bb = 0; bb < BB; ++bb) s += Cs[bb][tid];
        means[tid] = s / (float)BB;
    }
    __syncthreads();
    if (tid < DD) {
        const float m = means[tid];
        for (int bb = 0; bb < BB; ++bb) Cs[bb][tid] -= m;
    }
    __syncthreads();
    float ss = 0.f, dd2 = 0.f;
    const float invB1 = 1.f/63.f;
    for (int qi = tid; qi < 1024; qi += 256) {
        const int d  = dc*32 + qi / 32;
        const int e4 = (qi % 32) * 4;
        float a0=0,a1=0,a2=0,a3=0;
        for (int bb = 0; bb < BB; ++bb) {
            const float cd = Cs[bb][d];
            const float4 ce = *(const float4*)&Cs[bb][e4];
            a0 += cd*ce.x; a1 += cd*ce.y; a2 += cd*ce.z; a3 += cd*ce.w;
        }
        a0*=invB1; a1*=invB1; a2*=invB1; a3*=invB1;
        ss += a0*a0+a1*a1+a2*a2+a3*a3;
        if (d >= e4 && d < e4+4) {
            const float c[4] = {a0,a1,a2,a3};
            const float cd = c[d-e4];
            dd2 += cd*cd;
        }
    }
    reda[tid] = ss; redb[tid] = dd2;
    __syncthreads();
    for (int s2 = 128; s2 >= 1; s2 >>= 1) {
        if (tid < s2) { reda[tid] += reda[tid+s2]; redb[tid] += redb[tid+s2]; }
        __syncthreads();
    }
    if (tid == 0) partial[n*4 + dc] = 0.5f*(reda[0] - redb[0]);
}

// ---------------- K4: final attention + decov sum ----------------
__global__ __launch_bounds__(128) void k4_final(
    const float* __restrict__ x, const float* __restrict__ feature_mask,
    const float* __restrict__ fWq, const float* __restrict__ fbq,
    const float* __restrict__ fWk, const float* __restrict__ fbk,
    const float* __restrict__ fWv, const float* __restrict__ fbv,
    const float* __restrict__ mask_scale, const float* __restrict__ decov_partial,
    float* __restrict__ out)
{
    __shared__ float Xs[NN][DD];   // 38 KB
    __shared__ float fqs[DD], gs[DD], ys[DD];
    __shared__ float es[NN];
    __shared__ float sc[2];
    const int b = blockIdx.x;
    const int tid = threadIdx.x;
    for (int i = tid; i < NN*DD; i += 128) {
        const int r = i / DD, d = i % DD;
        Xs[r][d] = x[((size_t)b*NN + r)*DD + d];
    }
    __syncthreads();
    {   // fq = x[b, N-1] @ fWq + fbq
        float acc = 0.f;
        for (int d = 0; d < DD; ++d) acc += Xs[NN-1][d] * fWq[d*FAH + tid];
        fqs[tid] = acc + fbq[tid];
    }
    __syncthreads();
    {   // g = fWk @ fq ; c0 = fbk . fq
        float acc = 0.f;
        for (int a = 0; a < FAH; ++a) acc += fWk[tid*FAH + a] * fqs[a];
        gs[tid] = acc;
    }
    if (tid == 0) {
        float acc = 0.f;
        for (int a = 0; a < FAH; ++a) acc += fbk[a]*fqs[a];
        sc[0] = acc;
    }
    __syncthreads();
    const float msc = mask_scale[0];
    if (tid < NN) {   // fe[n] = x[n].g + c0 + msc*fm
        float acc = 0.f;
        for (int d = 0; d < DD; ++d) acc += Xs[tid][d]*gs[d];
        es[tid] = acc + sc[0] + msc * feature_mask[b*NN + tid];
    }
    __syncthreads();
    if (tid == 0) {
        float mx = -1e30f;
        for (int n2 = 0; n2 < NN; ++n2) mx = fmaxf(mx, es[n2]);
        float sum = 0.f;
        for (int n2 = 0; n2 < NN; ++n2) { const float e = expf(es[n2]-mx); es[n2] = e; sum += e; }
        sc[1] = 1.f/sum;
    }
    __syncthreads();
    {   // y = sum_n alpha[n] * x[n]
        const float inv = sc[1];
        float acc = 0.f;
        for (int n2 = 0; n2 < NN; ++n2) acc += es[n2]*Xs[n2][tid];
        ys[tid] = acc * inv;
    }
    __syncthreads();
    {   // pooled = y @ fWv + fbv   (valid since sum alpha = 1)
        float acc = 0.f;
        for (int d = 0; d < DD; ++d) acc += ys[d]*fWv[d*FAH + tid];
        out[(size_t)b*FAH + tid] = acc + fbv[tid];
    }
    if (b == 0 && tid == 0) {
        float s = 0.f;
        for (int i = 0; i < NN*4; ++i) s += decov_partial[i];
        out[BB*FAH] = s;
    }
}

extern "C" void kernel_launch(void* const* d_in, const int* in_sizes, int n_in,
                              void* d_out, int out_size, void* d_ws, size_t ws_size,
                              hipStream_t stream) {
    const float* H    = (const float*)d_in[0];
    const float* mask = (const float*)d_in[1];
    const float* fm   = (const float*)d_in[2];
    const float* Wt   = (const float*)d_in[3];
    const float* Wx   = (const float*)d_in[4];
    const float* rate = (const float*)d_in[5];
    const float* obs_bias  = (const float*)d_in[6];
    const float* miss_bias = (const float*)d_in[7];
    const float* Wq = (const float*)d_in[8];   const float* bq = (const float*)d_in[9];
    const float* Wk = (const float*)d_in[10];  const float* bk = (const float*)d_in[11];
    const float* Wv = (const float*)d_in[12];  const float* bv = (const float*)d_in[13];
    const float* Wo = (const float*)d_in[14];  const float* bo = (const float*)d_in[15];
    const float* ln1a = (const float*)d_in[16]; const float* ln1b = (const float*)d_in[17];
    const float* ln2a = (const float*)d_in[18]; const float* ln2b = (const float*)d_in[19];
    const float* w1 = (const float*)d_in[20];  const float* b1 = (const float*)d_in[21];
    const float* w2 = (const float*)d_in[22];  const float* b2 = (const float*)d_in[23];
    const float* fWq = (const float*)d_in[24]; const float* fbq = (const float*)d_in[25];
    const float* fWk = (const float*)d_in[26]; const float* fbk = (const float*)d_in[27];
    const float* fWv = (const float*)d_in[28]; const float* fbv = (const float*)d_in[29];
    const float* mask_scale = (const float*)d_in[30];
    float* out = (float*)d_out;

    float* ws = (float*)d_ws;
    const size_t S = (size_t)BN*DD;   // 622592 floats
    float* emb = ws;
    float* qb  = ws + 1*S;
    float* kb  = ws + 2*S;
    float* vb  = ws + 3*S;
    float* ctx = ws + 4*S;
    float* mha = ws + 5*S;
    float* x2  = ws + 6*S;
    float* dpart = ws + 7*S;          // 304 floats

    k1_temporal<<<K1GRID, 512, 0, stream>>>(H, mask, Wt, Wx, rate, obs_bias, miss_bias, emb);
    k2a_ln_qkv<<<NBLK, 256, 0, stream>>>(emb, ln1a, ln1b, Wq, bq, Wk, bk, Wv, bv, qb, kb, vb);
    k2b_attn<<<BB*NHEADS, 128, 0, stream>>>(qb, kb, vb, ctx);
    k23_proj_ffn<<<NBLK, 256, 0, stream>>>(ctx, emb, Wo, bo, ln2a, ln2b, w1, b1, w2, b2, mha, x2);
    k_decov<<<dim3(NN, 4), 256, 0, stream>>>(mha, dpart);
    k4_final<<<BB, 128, 0, stream>>>(x2, fm, fWq, fbq, fWk, fbk, fWv, fbv, mask_scale, dpart, out);
}

// Round 10
// 226.036 us; speedup vs baseline: 1.2450x; 1.2450x over previous
//
#include <hip/hip_runtime.h>
#include <hip/hip_bf16.h>
#include <math.h>

#define BB 64
#define NN 76
#define TT 128
#define DD 128
#define AH 8
#define NHEADS 4
#define DFF 512
#define FAH 128
#define DK 32
#define BN (BB*NN)        // 4864
#define ROWS 8
#define NBLK (BN/ROWS)    // 608
#define K1GRID 1024       // 4 blocks/CU; grid-stride over 4864 tiles

// LDS-only barrier: waits ds ops (lgkmcnt) but leaves global register loads
// (vmcnt) in flight across the barrier.
__device__ __forceinline__ void bar_lds() {
    asm volatile("s_waitcnt lgkmcnt(0)" ::: "memory");
    __builtin_amdgcn_s_barrier();
    __builtin_amdgcn_sched_barrier(0);
}

// ---------------- K1: missing-aware temporal attention ----------------
// Persistent-lite 1024 blocks x 512 thr (4/CU), grid-stride loop, NO prefetch
// (R8's proven one-shot body per tile). NEW: phase stagger -- co-resident
// blocks (bid, bid+256, bid+512, bid+768 under round-robin dispatch) sleep
// p * ~6200 cycles at start so the CU's 4 blocks run load phases and DS-heavy
// tails out of phase: one block streams HBM at full per-CU share while the
// others compute -> both pipes stay busy instead of convoying.
__global__ __launch_bounds__(512, 8) void k1_temporal(
    const float* __restrict__ H, const float* __restrict__ mask,
    const float* __restrict__ Wt, const float* __restrict__ Wx,
    const float* __restrict__ rate, const float* __restrict__ obs_bias,
    const float* __restrict__ miss_bias, float* __restrict__ emb)
{
    __shared__ __align__(16) float wtx[2*DD*AH];    // 8 KB: Wt then Wx
    __shared__ __align__(16) float wqs[DD];
    __shared__ __align__(16) float dots[TT];
    __shared__ __align__(16) float as_[TT];
    __shared__ __align__(16) float parts[16][DD];   // 8 KB
    __shared__ float qpart[2][AH];
    __shared__ float redsum[2];

    const int tid = threadIdx.x;
    const int lane = tid & 63, w = tid >> 6;
    const int c = tid & 31, g = tid >> 5;

    // one-time: stage Wt/Wx to LDS (1 float4/thread)
    const float* wsrc = (tid < 256) ? (Wt + 4*tid) : (Wx + 4*(tid-256));
    const float4 wld = *(const float4*)wsrc;
    const float sr   = 1.f / (1.f + expf(-rate[0]));
    const float obsv = obs_bias[0], missv = miss_bias[0];
    *(float4*)&wtx[4*tid] = wld;
    bar_lds();

    // phase stagger: p in {0,1,2,3}; each s_sleep(97) ~ 6208 cycles (~2.6 us)
    {
        const int p = (blockIdx.x >> 8) & 3;
        if (p >= 1) __builtin_amdgcn_s_sleep(97);
        if (p >= 2) __builtin_amdgcn_s_sleep(97);
        if (p >= 3) __builtin_amdgcn_s_sleep(97);
    }

    for (int t = blockIdx.x; t < BN; t += K1GRID) {
        const size_t base = (size_t)t * (TT*DD);

        // ---- issue this tile's loads (oldest: r127/mask, then h[8]) ----
        float r127 = 0.f, maskv = 0.f;
        if (tid < DD) {
            r127  = H[base + (TT-1)*DD + tid];
            maskv = mask[(size_t)t*TT + tid];
        }
        float4 h[8];
        const float4* Hg4 = (const float4*)(H + base);
        #pragma unroll
        for (int j = 0; j < 8; ++j) h[j] = Hg4[j*512 + tid];

        // q[a] = row127 . Wt[:,a]  (waves 0-1; Wt row from LDS)
        if (tid < DD) {
            float p[AH];
            #pragma unroll
            for (int a = 0; a < AH; ++a) p[a] = r127 * wtx[tid*AH + a];
            #pragma unroll
            for (int a = 0; a < AH; ++a) {
                float v = p[a];
                #pragma unroll
                for (int m = 1; m < 64; m <<= 1) v += __shfl_xor(v, m, 64);
                if (lane == 0) qpart[w][a] = v;
            }
        }
        bar_lds();
        // wq[d] = sum_a q[a]*Wx[d,a]
        if (tid < DD) {
            float acc = 0.f;
            #pragma unroll
            for (int a = 0; a < AH; ++a)
                acc += (qpart[0][a] + qpart[1][a]) * wtx[DD*AH + tid*AH + a];
            wqs[tid] = acc;
        }
        bar_lds();

        // dot[t] = H[t].wq ; rows t = g + 16j; 32-lane group reduce
        const float4 wq4 = *(const float4*)&wqs[4*c];
        #pragma unroll
        for (int j = 0; j < 8; ++j) {
            float p = h[j].x*wq4.x + h[j].y*wq4.y + h[j].z*wq4.z + h[j].w*wq4.w;
            #pragma unroll
            for (int m = 1; m < 32; m <<= 1) p += __shfl_xor(p, m, 64);
            if (c == 0) dots[g + 16*j] = p;
        }
        bar_lds();

        // e[t] + UNNORMALIZED exp (e bounded ~2.6 -> no max subtraction);
        // 1/sum folded into the emb store.
        if (tid < TT) {
            const float dot = dots[tid];
            const float sig = 1.f / (1.f + expf(-dot));
            const float bt  = (float)(TT - tid);
            const float denom = sr * (logf(2.72f + (1.f - sig)) * bt);
            float e = fmaxf(sig / denom, 0.f);
            e += (maskv > 0.5f) ? obsv : missv;
            const float ex = expf(e);
            as_[tid] = ex;
            float vs = ex;
            #pragma unroll
            for (int m = 1; m < 64; m <<= 1) vs += __shfl_xor(vs, m, 64);
            if (lane == 0) redsum[w] = vs;
        }
        bar_lds();
        const float inv = 1.f / (redsum[0] + redsum[1]);

        // emb[d] = inv * sum_t ex[t]*H[t,d]
        float4 facc = make_float4(0.f, 0.f, 0.f, 0.f);
        #pragma unroll
        for (int j = 0; j < 8; ++j) {
            const float a = as_[g + 16*j];
            facc.x += a*h[j].x; facc.y += a*h[j].y;
            facc.z += a*h[j].z; facc.w += a*h[j].w;
        }
        *(float4*)&parts[g][4*c] = facc;
        bar_lds();
        if (tid < DD) {
            float acc = 0.f;
            #pragma unroll
            for (int gg = 0; gg < 16; ++gg) acc += parts[gg][tid];
            emb[(size_t)t*DD + tid] = acc * inv;
        }
        bar_lds();   // parts/as_ reused next iteration
    }
}

// ---------------- K2a: LN1 + Q/K/V projections ----------------
__global__ __launch_bounds__(256) void k2a_ln_qkv(
    const float* __restrict__ emb,
    const float* __restrict__ ln_a, const float* __restrict__ ln_b,
    const float* __restrict__ Wq, const float* __restrict__ bq,
    const float* __restrict__ Wk, const float* __restrict__ bk,
    const float* __restrict__ Wv, const float* __restrict__ bv,
    float* __restrict__ qb, float* __restrict__ kb, float* __restrict__ vb)
{
    __shared__ float xs[ROWS][DD];
    const int tid = threadIdx.x;
    const int r0 = blockIdx.x * ROWS;

    for (int i = tid; i < ROWS*DD; i += 256) {
        const int r = i / DD, d = i % DD;
        xs[r][d] = emb[(size_t)(r0+r)*DD + d];
    }
    __syncthreads();

    {   // LayerNorm (ddof=1, eps added to std); wave w -> rows 2w,2w+1
        const int wv_ = tid >> 6, lane = tid & 63;
        for (int rr = 0; rr < 2; ++rr) {
            const int r = wv_*2 + rr;
            const float x0 = xs[r][lane], x1 = xs[r][lane+64];
            float s = x0 + x1;
            #pragma unroll
            for (int m = 1; m < 64; m <<= 1) s += __shfl_xor(s, m, 64);
            const float mean = s / (float)DD;
            const float d0 = x0 - mean, d1 = x1 - mean;
            float v = d0*d0 + d1*d1;
            #pragma unroll
            for (int m = 1; m < 64; m <<= 1) v += __shfl_xor(v, m, 64);
            const float inv = 1.f / (sqrtf(v / (float)(DD-1)) + 1e-7f);
            xs[r][lane]    = ln_a[lane]   * (d0*inv) + ln_b[lane];
            xs[r][lane+64] = ln_a[lane+64]* (d1*inv) + ln_b[lane+64];
        }
    }
    __syncthreads();

    const int j = tid & 127, half = tid >> 7, rbase = half*4;
    float aq[4] = {0,0,0,0}, ak[4] = {0,0,0,0}, av[4] = {0,0,0,0};
    for (int d = 0; d < DD; ++d) {
        const float wqv = Wq[d*DD+j], wkv = Wk[d*DD+j], wvv = Wv[d*DD+j];
        #pragma unroll
        for (int r = 0; r < 4; ++r) {
            const float xv = xs[rbase+r][d];
            aq[r] += xv*wqv; ak[r] += xv*wkv; av[r] += xv*wvv;
        }
    }
    const float bqv = bq[j], bkv = bk[j], bvv = bv[j];
    #pragma unroll
    for (int r = 0; r < 4; ++r) {
        const size_t o = (size_t)(r0 + rbase + r)*DD + j;
        qb[o] = aq[r]+bqv; kb[o] = ak[r]+bkv; vb[o] = av[r]+bvv;
    }
}

// ---------------- K2b: per-(b,head) self-attention over N ----------------
__global__ __launch_bounds__(128) void k2b_attn(
    const float* __restrict__ qb, const float* __restrict__ kb,
    const float* __restrict__ vb, float* __restrict__ ctx)
{
    __shared__ float Qs[NN][DK], Ks[NN][DK], Vs[NN][DK];
    __shared__ float Ps[NN][NN+1];   // stride 77: bank-conflict-free
    const int b = blockIdx.x / NHEADS, h = blockIdx.x % NHEADS;
    const int tid = threadIdx.x;
    const int co = h*DK;

    for (int i = tid; i < NN*DK; i += 128) {
        const int r = i / DK, c = i % DK;
        const size_t o = (size_t)(b*NN + r)*DD + co + c;
        Qs[r][c] = qb[o]; Ks[r][c] = kb[o]; Vs[r][c] = vb[o];
    }
    __syncthreads();

    const float scale = 0.17677669529663687f;   // 1/sqrt(32)
    if (tid < NN) {
        float qr[DK];
        #pragma unroll
        for (int c = 0; c < DK; ++c) qr[c] = Qs[tid][c];
        float mx = -1e30f;
        for (int k = 0; k < NN; ++k) {
            float s = 0.f;
            #pragma unroll
            for (int c = 0; c < DK; ++c) s += qr[c]*Ks[k][c];
            s *= scale;
            Ps[tid][k] = s;
            mx = fmaxf(mx, s);
        }
        float sum = 0.f;
        for (int k = 0; k < NN; ++k) { const float e = expf(Ps[tid][k]-mx); Ps[tid][k] = e; sum += e; }
        const float inv = 1.f/sum;
        float acc[DK];
        #pragma unroll
        for (int c = 0; c < DK; ++c) acc[c] = 0.f;
        for (int k = 0; k < NN; ++k) {
            const float p = Ps[tid][k];
            #pragma unroll
            for (int c = 0; c < DK; ++c) acc[c] += p*Vs[k][c];
        }
        const size_t o = (size_t)(b*NN + tid)*DD + co;
        #pragma unroll
        for (int c = 0; c < DK; ++c) ctx[o+c] = acc[c]*inv;
    }
}

// ---------------- K23: Wo projection + residual + LN2 + FFN + residual ----
__global__ __launch_bounds__(256) void k23_proj_ffn(
    const float* __restrict__ ctx, const float* __restrict__ emb,
    const float* __restrict__ Wo, const float* __restrict__ bo,
    const float* __restrict__ ln_a, const float* __restrict__ ln_b,
    const float* __restrict__ w1, const float* __restrict__ b1,
    const float* __restrict__ w2, const float* __restrict__ b2,
    float* __restrict__ mha, float* __restrict__ x2)
{
    __shared__ float cs[ROWS][DD];        // ctx rows
    __shared__ float xs[ROWS][DD];        // x = emb + mha
    __shared__ float x1s[ROWS][DD];       // LN2(x)
    __shared__ float hs[ROWS][DFF];       // 16 KB
    __shared__ float parts[2][ROWS][DD];  // 8 KB
    const int tid = threadIdx.x;
    const int r0 = blockIdx.x * ROWS;

    for (int i = tid; i < ROWS*DD; i += 256) {
        const int r = i / DD, d = i % DD;
        cs[r][d] = ctx[(size_t)(r0+r)*DD + d];
    }
    __syncthreads();

    {   // mha = ctx @ Wo + bo ; x = emb + mha (LDS); mha -> global
        const int j = tid & 127, half = tid >> 7, rbase = half*4;
        float acc[4] = {0,0,0,0};
        for (int d = 0; d < DD; ++d) {
            const float wv = Wo[d*DD+j];
            #pragma unroll
            for (int r = 0; r < 4; ++r) acc[r] += cs[rbase+r][d]*wv;
        }
        const float bov = bo[j];
        #pragma unroll
        for (int r = 0; r < 4; ++r) {
            const size_t o = (size_t)(r0+rbase+r)*DD + j;
            const float m = acc[r] + bov;
            mha[o] = m;
            xs[rbase+r][j] = emb[o] + m;
        }
    }
    __syncthreads();

    {   // LN2
        const int wv_ = tid >> 6, lane = tid & 63;
        for (int rr = 0; rr < 2; ++rr) {
            const int r = wv_*2 + rr;
            const float v0 = xs[r][lane], v1 = xs[r][lane+64];
            float s = v0 + v1;
            #pragma unroll
            for (int m = 1; m < 64; m <<= 1) s += __shfl_xor(s, m, 64);
            const float mean = s / (float)DD;
            const float d0 = v0-mean, d1 = v1-mean;
            float vv = d0*d0 + d1*d1;
            #pragma unroll
            for (int m = 1; m < 64; m <<= 1) vv += __shfl_xor(vv, m, 64);
            const float inv = 1.f / (sqrtf(vv/(float)(DD-1)) + 1e-7f);
            x1s[r][lane]    = ln_a[lane]   * (d0*inv) + ln_b[lane];
            x1s[r][lane+64] = ln_a[lane+64]* (d1*inv) + ln_b[lane+64];
        }
    }
    __syncthreads();

    {   // h = relu(x1 @ w1 + b1) ; thread -> cols tid, tid+256
        float acc0[ROWS], acc1[ROWS];
        #pragma unroll
        for (int r = 0; r < ROWS; ++r) { acc0[r]=0.f; acc1[r]=0.f; }
        for (int d = 0; d < DD; ++d) {
            const float wv0 = w1[d*DFF + tid], wv1 = w1[d*DFF + tid + 256];
            #pragma unroll
            for (int r = 0; r < ROWS; ++r) {
                const float xv = x1s[r][d];
                acc0[r] += xv*wv0; acc1[r] += xv*wv1;
            }
        }
        const float b10 = b1[tid], b11 = b1[tid+256];
        #pragma unroll
        for (int r = 0; r < ROWS; ++r) {
            hs[r][tid]     = fmaxf(acc0[r]+b10, 0.f);
            hs[r][tid+256] = fmaxf(acc1[r]+b11, 0.f);
        }
    }
    __syncthreads();

    {   // ffn = h @ w2 + b2 ; x2 = x + ffn
        const int j = tid & 127, half = tid >> 7;
        float acc[ROWS];
        #pragma unroll
        for (int r = 0; r < ROWS; ++r) acc[r] = 0.f;
        for (int k = half*256; k < half*256 + 256; ++k) {
            const float wv = w2[k*DD + j];
            #pragma unroll
            for (int r = 0; r < ROWS; ++r) acc[r] += hs[r][k]*wv;
        }
        #pragma unroll
        for (int r = 0; r < ROWS; ++r) parts[half][r][j] = acc[r];
        __syncthreads();
        if (half == 0) {
            const float b2v = b2[j];
            #pragma unroll
            for (int r = 0; r < ROWS; ++r) {
                const size_t o = (size_t)(r0+r)*DD + j;
                x2[o] = xs[r][j] + parts[0][r][j] + parts[1][r][j] + b2v;
            }
        }
    }
}

// ---------------- K-decov: DeCov partials per (n, d-chunk) ----------------
__global__ __launch_bounds__(256) void k_decov(
    const float* __restrict__ mha, float* __restrict__ partial)
{
    __shared__ float Cs[BB][DD];     // 32 KB
    __shared__ float means[DD];
    __shared__ float reda[256];
    __shared__ float redb[256];
    const int n = blockIdx.x, dc = blockIdx.y;
    const int tid = threadIdx.x;
    for (int i = tid; i < BB*DD; i += 256) {
        const int bb = i / DD, d = i % DD;
        Cs[bb][d] = mha[((size_t)bb*NN + n)*DD + d];
    }
    __syncthreads();
    if (tid < DD) {
        float s = 0.f;
        for (int bb = 0; bb < BB; ++bb) s += Cs[bb][tid];
        means[tid] = s / (float)BB;
    }
    __syncthreads();
    if (tid < DD) {
        const float m = means[tid];
        for (int bb = 0; bb < BB; ++bb) Cs[bb][tid] -= m;
    }
    __syncthreads();
    float ss = 0.f, dd2 = 0.f;
    const float invB1 = 1.f/63.f;
    for (int qi = tid; qi < 1024; qi += 256) {
        const int d  = dc*32 + qi / 32;
        const int e4 = (qi % 32) * 4;
        float a0=0,a1=0,a2=0,a3=0;
        for (int bb = 0; bb < BB; ++bb) {
            const float cd = Cs[bb][d];
            const float4 ce = *(const float4*)&Cs[bb][e4];
            a0 += cd*ce.x; a1 += cd*ce.y; a2 += cd*ce.z; a3 += cd*ce.w;
        }
        a0*=invB1; a1*=invB1; a2*=invB1; a3*=invB1;
        ss += a0*a0+a1*a1+a2*a2+a3*a3;
        if (d >= e4 && d < e4+4) {
            const float c[4] = {a0,a1,a2,a3};
            const float cd = c[d-e4];
            dd2 += cd*cd;
        }
    }
    reda[tid] = ss; redb[tid] = dd2;
    __syncthreads();
    for (int s2 = 128; s2 >= 1; s2 >>= 1) {
        if (tid < s2) { reda[tid] += reda[tid+s2]; redb[tid] += redb[tid+s2]; }
        __syncthreads();
    }
    if (tid == 0) partial[n*4 + dc] = 0.5f*(reda[0] - redb[0]);
}

// ---------------- K4: final attention + decov sum ----------------
__global__ __launch_bounds__(128) void k4_final(
    const float* __restrict__ x, const float* __restrict__ feature_mask,
    const float* __restrict__ fWq, const float* __restrict__ fbq,
    const float* __restrict__ fWk, const float* __restrict__ fbk,
    const float* __restrict__ fWv, const float* __restrict__ fbv,
    const float* __restrict__ mask_scale, const float* __restrict__ decov_partial,
    float* __restrict__ out)
{
    __shared__ float Xs[NN][DD];   // 38 KB
    __shared__ float fqs[DD], gs[DD], ys[DD];
    __shared__ float es[NN];
    __shared__ float sc[2];
    const int b = blockIdx.x;
    const int tid = threadIdx.x;
    for (int i = tid; i < NN*DD; i += 128) {
        const int r = i / DD, d = i % DD;
        Xs[r][d] = x[((size_t)b*NN + r)*DD + d];
    }
    __syncthreads();
    {   // fq = x[b, N-1] @ fWq + fbq
        float acc = 0.f;
        for (int d = 0; d < DD; ++d) acc += Xs[NN-1][d] * fWq[d*FAH + tid];
        fqs[tid] = acc + fbq[tid];
    }
    __syncthreads();
    {   // g = fWk @ fq ; c0 = fbk . fq
        float acc = 0.f;
        for (int a = 0; a < FAH; ++a) acc += fWk[tid*FAH + a] * fqs[a];
        gs[tid] = acc;
    }
    if (tid == 0) {
        float acc = 0.f;
        for (int a = 0; a < FAH; ++a) acc += fbk[a]*fqs[a];
        sc[0] = acc;
    }
    __syncthreads();
    const float msc = mask_scale[0];
    if (tid < NN) {   // fe[n] = x[n].g + c0 + msc*fm
        float acc = 0.f;
        for (int d = 0; d < DD; ++d) acc += Xs[tid][d]*gs[d];
        es[tid] = acc + sc[0] + msc * feature_mask[b*NN + tid];
    }
    __syncthreads();
    if (tid == 0) {
        float mx = -1e30f;
        for (int n2 = 0; n2 < NN; ++n2) mx = fmaxf(mx, es[n2]);
        float sum = 0.f;
        for (int n2 = 0; n2 < NN; ++n2) { const float e = expf(es[n2]-mx); es[n2] = e; sum += e; }
        sc[1] = 1.f/sum;
    }
    __syncthreads();
    {   // y = sum_n alpha[n] * x[n]
        const float inv = sc[1];
        float acc = 0.f;
        for (int n2 = 0; n2 < NN; ++n2) acc += es[n2]*Xs[n2][tid];
        ys[tid] = acc * inv;
    }
    __syncthreads();
    {   // pooled = y @ fWv + fbv   (valid since sum alpha = 1)
        float acc = 0.f;
        for (int d = 0; d < DD; ++d) acc += ys[d]*fWv[d*FAH + tid];
        out[(size_t)b*FAH + tid] = acc + fbv[tid];
    }
    if (b == 0 && tid == 0) {
        float s = 0.f;
        for (int i = 0; i < NN*4; ++i) s += decov_partial[i];
        out[BB*FAH] = s;
    }
}

extern "C" void kernel_launch(void* const* d_in, const int* in_sizes, int n_in,
                              void* d_out, int out_size, void* d_ws, size_t ws_size,
                              hipStream_t stream) {
    const float* H    = (const float*)d_in[0];
    const float* mask = (const float*)d_in[1];
    const float* fm   = (const float*)d_in[2];
    const float* Wt   = (const float*)d_in[3];
    const float* Wx   = (const float*)d_in[4];
    const float* rate = (const float*)d_in[5];
    const float* obs_bias  = (const float*)d_in[6];
    const float* miss_bias = (const float*)d_in[7];
    const float* Wq = (const float*)d_in[8];   const float* bq = (const float*)d_in[9];
    const float* Wk = (const float*)d_in[10];  const float* bk = (const float*)d_in[11];
    const float* Wv = (const float*)d_in[12];  const float* bv = (const float*)d_in[13];
    const float* Wo = (const float*)d_in[14];  const float* bo = (const float*)d_in[15];
    const float* ln1a = (const float*)d_in[16]; const float* ln1b = (const float*)d_in[17];
    const float* ln2a = (const float*)d_in[18]; const float* ln2b = (const float*)d_in[19];
    const float* w1 = (const float*)d_in[20];  const float* b1 = (const float*)d_in[21];
    const float* w2 = (const float*)d_in[22];  const float* b2 = (const float*)d_in[23];
    const float* fWq = (const float*)d_in[24]; const float* fbq = (const float*)d_in[25];
    const float* fWk = (const float*)d_in[26]; const float* fbk = (const float*)d_in[27];
    const float* fWv = (const float*)d_in[28]; const float* fbv = (const float*)d_in[29];
    const float* mask_scale = (const float*)d_in[30];
    float* out = (float*)d_out;

    float* ws = (float*)d_ws;
    const size_t S = (size_t)BN*DD;   // 622592 floats
    float* emb = ws;
    float* qb  = ws + 1*S;
    float* kb  = ws + 2*S;
    float* vb  = ws + 3*S;
    float* ctx = ws + 4*S;
    float* mha = ws + 5*S;
    float* x2  = ws + 6*S;
    float* dpart = ws + 7*S;          // 304 floats

    k1_temporal<<<K1GRID, 512, 0, stream>>>(H, mask, Wt, Wx, rate, obs_bias, miss_bias, emb);
    k2a_ln_qkv<<<NBLK, 256, 0, stream>>>(emb, ln1a, ln1b, Wq, bq, Wk, bk, Wv, bv, qb, kb, vb);
    k2b_attn<<<BB*NHEADS, 128, 0, stream>>>(qb, kb, vb, ctx);
    k23_proj_ffn<<<NBLK, 256, 0, stream>>>(ctx, emb, Wo, bo, ln2a, ln2b, w1, b1, w2, b2, mha, x2);
    k_decov<<<dim3(NN, 4), 256, 0, stream>>>(mha, dpart);
    k4_final<<<BB, 128, 0, stream>>>(x2, fm, fWq, fbq, fWk, fbk, fWv, fbv, mask_scale, dpart, out);
}

// Round 11
// 225.246 us; speedup vs baseline: 1.2493x; 1.0035x over previous
//
#include <hip/hip_runtime.h>
#include <hip/hip_bf16.h>
#include <math.h>

#define BB 64
#define NN 76
#define TT 128
#define DD 128
#define AH 8
#define NHEADS 4
#define DFF 512
#define FAH 128
#define DK 32
#define BN (BB*NN)        // 4864
#define ROWS 16           // rows per block for k2a/k23
#define NBLK (BN/ROWS)    // 304

// LDS-only barrier: waits ds ops (lgkmcnt) but leaves global register loads
// (vmcnt) in flight across the barrier.
__device__ __forceinline__ void bar_lds() {
    asm volatile("s_waitcnt lgkmcnt(0)" ::: "memory");
    __builtin_amdgcn_s_barrier();
    __builtin_amdgcn_sched_barrier(0);
}

// ---------------- K1: missing-aware temporal attention (R8, frozen) -------
__global__ __launch_bounds__(512, 8) void k1_temporal(
    const float* __restrict__ H, const float* __restrict__ mask,
    const float* __restrict__ Wt, const float* __restrict__ Wx,
    const float* __restrict__ rate, const float* __restrict__ obs_bias,
    const float* __restrict__ miss_bias, float* __restrict__ emb)
{
    __shared__ __align__(16) float wtx[2*DD*AH];    // 8 KB: Wt then Wx
    __shared__ __align__(16) float wqs[DD];
    __shared__ __align__(16) float dots[TT];
    __shared__ __align__(16) float as_[TT];
    __shared__ __align__(16) float parts[16][DD];   // 8 KB
    __shared__ float qpart[2][AH];
    __shared__ float redsum[2];

    const int bid = blockIdx.x;   // b*N + n
    const int tid = threadIdx.x;
    const size_t base = (size_t)bid * (TT*DD);
    const int lane = tid & 63, w = tid >> 6;
    const int c = tid & 31, g = tid >> 5;

    // ---- oldest loads: weights chunk (1 float4/thread), r127, mask ----
    const float* wsrc = (tid < 256) ? (Wt + 4*tid) : (Wx + 4*(tid-256));
    const float4 wld = *(const float4*)wsrc;
    float r127 = 0.f, maskv = 0.f;
    if (tid < DD) {
        r127  = H[base + (TT-1)*DD + tid];
        maskv = mask[(size_t)bid*TT + tid];
    }
    const float sr   = 1.f / (1.f + expf(-rate[0]));
    const float obsv = obs_bias[0], missv = miss_bias[0];

    // ---- tile loads (youngest; stay in flight until the dot phase) ----
    float4 h[8];
    const float4* Hg4 = (const float4*)(H + base);
    #pragma unroll
    for (int j = 0; j < 8; ++j) h[j] = Hg4[j*512 + tid];

    // stage weights to LDS (waits only the oldest vmcnt entries)
    *(float4*)&wtx[4*tid] = wld;
    bar_lds();

    // q[a] = row127 . Wt[:,a]  (waves 0-1; Wt row from LDS)
    if (tid < DD) {
        float p[AH];
        #pragma unroll
        for (int a = 0; a < AH; ++a) p[a] = r127 * wtx[tid*AH + a];
        #pragma unroll
        for (int a = 0; a < AH; ++a) {
            float v = p[a];
            #pragma unroll
            for (int m = 1; m < 64; m <<= 1) v += __shfl_xor(v, m, 64);
            if (lane == 0) qpart[w][a] = v;
        }
    }
    bar_lds();
    // wq[d] = sum_a q[a]*Wx[d,a]  (Wx row from LDS)
    if (tid < DD) {
        float acc = 0.f;
        #pragma unroll
        for (int a = 0; a < AH; ++a)
            acc += (qpart[0][a] + qpart[1][a]) * wtx[DD*AH + tid*AH + a];
        wqs[tid] = acc;
    }
    bar_lds();

    // dot[t] = H[t] . wq ; rows t = g + 16j; 32-lane group reduce
    const float4 wq4 = *(const float4*)&wqs[4*c];
    #pragma unroll
    for (int j = 0; j < 8; ++j) {
        float p = h[j].x*wq4.x + h[j].y*wq4.y + h[j].z*wq4.z + h[j].w*wq4.w;
        #pragma unroll
        for (int m = 1; m < 32; m <<= 1) p += __shfl_xor(p, m, 64);
        if (c == 0) dots[g + 16*j] = p;
    }
    bar_lds();

    // e[t] + UNNORMALIZED exp (e bounded ~2.6 -> no max subtraction);
    // sum reduce only; 1/sum folded into the emb store.
    if (tid < TT) {
        const float dot = dots[tid];
        const float sig = 1.f / (1.f + expf(-dot));
        const float bt  = (float)(TT - tid);
        const float denom = sr * (logf(2.72f + (1.f - sig)) * bt);
        float e = fmaxf(sig / denom, 0.f);
        e += (maskv > 0.5f) ? obsv : missv;
        const float ex = expf(e);
        as_[tid] = ex;
        float vs = ex;
        #pragma unroll
        for (int m = 1; m < 64; m <<= 1) vs += __shfl_xor(vs, m, 64);
        if (lane == 0) redsum[w] = vs;
    }
    bar_lds();
    const float inv = 1.f / (redsum[0] + redsum[1]);

    // emb[d] = inv * sum_t ex[t]*H[t,d]  (register-local, 16-way combine)
    float4 facc = make_float4(0.f, 0.f, 0.f, 0.f);
    #pragma unroll
    for (int j = 0; j < 8; ++j) {
        const float a = as_[g + 16*j];
        facc.x += a*h[j].x; facc.y += a*h[j].y;
        facc.z += a*h[j].z; facc.w += a*h[j].w;
    }
    *(float4*)&parts[g][4*c] = facc;
    bar_lds();
    if (tid < DD) {
        float acc = 0.f;
        #pragma unroll
        for (int gg = 0; gg < 16; ++gg) acc += parts[gg][tid];
        emb[(size_t)bid*DD + tid] = acc * inv;
    }
}

// ---------------- K2a: LN1 + Q/K/V projections (16 rows/block) ------------
__global__ __launch_bounds__(256) void k2a_ln_qkv(
    const float* __restrict__ emb,
    const float* __restrict__ ln_a, const float* __restrict__ ln_b,
    const float* __restrict__ Wq, const float* __restrict__ bq,
    const float* __restrict__ Wk, const float* __restrict__ bk,
    const float* __restrict__ Wv, const float* __restrict__ bv,
    float* __restrict__ qb, float* __restrict__ kb, float* __restrict__ vb)
{
    __shared__ float xs[ROWS][DD];     // 8 KB
    const int tid = threadIdx.x;
    const int r0 = blockIdx.x * ROWS;

    for (int i = tid; i < ROWS*DD; i += 256) {
        const int r = i / DD, d = i % DD;
        xs[r][d] = emb[(size_t)(r0+r)*DD + d];
    }
    __syncthreads();

    {   // LayerNorm (ddof=1, eps added to std); wave w -> rows 4w..4w+3
        const int wv_ = tid >> 6, lane = tid & 63;
        for (int rr = 0; rr < 4; ++rr) {
            const int r = wv_*4 + rr;
            const float x0 = xs[r][lane], x1 = xs[r][lane+64];
            float s = x0 + x1;
            #pragma unroll
            for (int m = 1; m < 64; m <<= 1) s += __shfl_xor(s, m, 64);
            const float mean = s / (float)DD;
            const float d0 = x0 - mean, d1 = x1 - mean;
            float v = d0*d0 + d1*d1;
            #pragma unroll
            for (int m = 1; m < 64; m <<= 1) v += __shfl_xor(v, m, 64);
            const float inv = 1.f / (sqrtf(v / (float)(DD-1)) + 1e-7f);
            xs[r][lane]    = ln_a[lane]   * (d0*inv) + ln_b[lane];
            xs[r][lane+64] = ln_a[lane+64]* (d1*inv) + ln_b[lane+64];
        }
    }
    __syncthreads();

    const int j = tid & 127, half = tid >> 7, rbase = half*8;
    float aq[8] = {0}, ak[8] = {0}, av[8] = {0};
    for (int d = 0; d < DD; ++d) {
        const float wqv = Wq[d*DD+j], wkv = Wk[d*DD+j], wvv = Wv[d*DD+j];
        #pragma unroll
        for (int r = 0; r < 8; ++r) {
            const float xv = xs[rbase+r][d];
            aq[r] += xv*wqv; ak[r] += xv*wkv; av[r] += xv*wvv;
        }
    }
    const float bqv = bq[j], bkv = bk[j], bvv = bv[j];
    #pragma unroll
    for (int r = 0; r < 8; ++r) {
        const size_t o = (size_t)(r0 + rbase + r)*DD + j;
        qb[o] = aq[r]+bqv; kb[o] = ak[r]+bkv; vb[o] = av[r]+bvv;
    }
}

// ---------------- K2b: per-(b,head) self-attention over N ----------------
__global__ __launch_bounds__(128) void k2b_attn(
    const float* __restrict__ qb, const float* __restrict__ kb,
    const float* __restrict__ vb, float* __restrict__ ctx)
{
    __shared__ float Qs[NN][DK], Ks[NN][DK], Vs[NN][DK];
    __shared__ float Ps[NN][NN+1];   // stride 77: bank-conflict-free
    const int b = blockIdx.x / NHEADS, h = blockIdx.x % NHEADS;
    const int tid = threadIdx.x;
    const int co = h*DK;

    for (int i = tid; i < NN*DK; i += 128) {
        const int r = i / DK, c = i % DK;
        const size_t o = (size_t)(b*NN + r)*DD + co + c;
        Qs[r][c] = qb[o]; Ks[r][c] = kb[o]; Vs[r][c] = vb[o];
    }
    __syncthreads();

    const float scale = 0.17677669529663687f;   // 1/sqrt(32)
    if (tid < NN) {
        float qr[DK];
        #pragma unroll
        for (int c = 0; c < DK; ++c) qr[c] = Qs[tid][c];
        float mx = -1e30f;
        for (int k = 0; k < NN; ++k) {
            float s = 0.f;
            #pragma unroll
            for (int c = 0; c < DK; ++c) s += qr[c]*Ks[k][c];
            s *= scale;
            Ps[tid][k] = s;
            mx = fmaxf(mx, s);
        }
        float sum = 0.f;
        for (int k = 0; k < NN; ++k) { const float e = expf(Ps[tid][k]-mx); Ps[tid][k] = e; sum += e; }
        const float inv = 1.f/sum;
        float acc[DK];
        #pragma unroll
        for (int c = 0; c < DK; ++c) acc[c] = 0.f;
        for (int k = 0; k < NN; ++k) {
            const float p = Ps[tid][k];
            #pragma unroll
            for (int c = 0; c < DK; ++c) acc[c] += p*Vs[k][c];
        }
        const size_t o = (size_t)(b*NN + tid)*DD + co;
        #pragma unroll
        for (int c = 0; c < DK; ++c) ctx[o+c] = acc[c]*inv;
    }
}

// ---- K23: Wo proj + residual + LN2 + FFN + residual (16 rows/block) ------
// Also zeroes the decov accumulator out[BB*FAH] (block 0) for the next launch.
__global__ __launch_bounds__(256) void k23_proj_ffn(
    const float* __restrict__ ctx, const float* __restrict__ emb,
    const float* __restrict__ Wo, const float* __restrict__ bo,
    const float* __restrict__ ln_a, const float* __restrict__ ln_b,
    const float* __restrict__ w1, const float* __restrict__ b1,
    const float* __restrict__ w2, const float* __restrict__ b2,
    float* __restrict__ mha, float* __restrict__ x2, float* __restrict__ out)
{
    __shared__ float cs[ROWS][DD];        // 8 KB
    __shared__ float xs[ROWS][DD];        // 8 KB
    __shared__ float x1s[ROWS][DD];       // 8 KB
    __shared__ float hs[ROWS][DFF];       // 32 KB
    __shared__ float parts[2][ROWS][DD];  // 16 KB
    const int tid = threadIdx.x;
    const int r0 = blockIdx.x * ROWS;

    if (blockIdx.x == 0 && tid == 0) out[BB*FAH] = 0.f;   // decov acc reset

    for (int i = tid; i < ROWS*DD; i += 256) {
        const int r = i / DD, d = i % DD;
        cs[r][d] = ctx[(size_t)(r0+r)*DD + d];
    }
    __syncthreads();

    {   // mha = ctx @ Wo + bo ; x = emb + mha (LDS); mha -> global
        const int j = tid & 127, half = tid >> 7, rbase = half*8;
        float acc[8] = {0};
        for (int d = 0; d < DD; ++d) {
            const float wv = Wo[d*DD+j];
            #pragma unroll
            for (int r = 0; r < 8; ++r) acc[r] += cs[rbase+r][d]*wv;
        }
        const float bov = bo[j];
        #pragma unroll
        for (int r = 0; r < 8; ++r) {
            const size_t o = (size_t)(r0+rbase+r)*DD + j;
            const float m = acc[r] + bov;
            mha[o] = m;
            xs[rbase+r][j] = emb[o] + m;
        }
    }
    __syncthreads();

    {   // LN2; wave w -> rows 4w..4w+3
        const int wv_ = tid >> 6, lane = tid & 63;
        for (int rr = 0; rr < 4; ++rr) {
            const int r = wv_*4 + rr;
            const float v0 = xs[r][lane], v1 = xs[r][lane+64];
            float s = v0 + v1;
            #pragma unroll
            for (int m = 1; m < 64; m <<= 1) s += __shfl_xor(s, m, 64);
            const float mean = s / (float)DD;
            const float d0 = v0-mean, d1 = v1-mean;
            float vv = d0*d0 + d1*d1;
            #pragma unroll
            for (int m = 1; m < 64; m <<= 1) vv += __shfl_xor(vv, m, 64);
            const float inv = 1.f / (sqrtf(vv/(float)(DD-1)) + 1e-7f);
            x1s[r][lane]    = ln_a[lane]   * (d0*inv) + ln_b[lane];
            x1s[r][lane+64] = ln_a[lane+64]* (d1*inv) + ln_b[lane+64];
        }
    }
    __syncthreads();

    {   // h = relu(x1 @ w1 + b1) ; thread -> cols tid, tid+256
        float acc0[ROWS], acc1[ROWS];
        #pragma unroll
        for (int r = 0; r < ROWS; ++r) { acc0[r]=0.f; acc1[r]=0.f; }
        for (int d = 0; d < DD; ++d) {
            const float wv0 = w1[d*DFF + tid], wv1 = w1[d*DFF + tid + 256];
            #pragma unroll
            for (int r = 0; r < ROWS; ++r) {
                const float xv = x1s[r][d];
                acc0[r] += xv*wv0; acc1[r] += xv*wv1;
            }
        }
        const float b10 = b1[tid], b11 = b1[tid+256];
        #pragma unroll
        for (int r = 0; r < ROWS; ++r) {
            hs[r][tid]     = fmaxf(acc0[r]+b10, 0.f);
            hs[r][tid+256] = fmaxf(acc1[r]+b11, 0.f);
        }
    }
    __syncthreads();

    {   // ffn = h @ w2 + b2 ; x2 = x + ffn
        const int j = tid & 127, half = tid >> 7;
        float acc[ROWS];
        #pragma unroll
        for (int r = 0; r < ROWS; ++r) acc[r] = 0.f;
        for (int k = half*256; k < half*256 + 256; ++k) {
            const float wv = w2[k*DD + j];
            #pragma unroll
            for (int r = 0; r < ROWS; ++r) acc[r] += hs[r][k]*wv;
        }
        #pragma unroll
        for (int r = 0; r < ROWS; ++r) parts[half][r][j] = acc[r];
        __syncthreads();
        if (half == 0) {
            const float b2v = b2[j];
            #pragma unroll
            for (int r = 0; r < ROWS; ++r) {
                const size_t o = (size_t)(r0+r)*DD + j;
                x2[o] = xs[r][j] + parts[0][r][j] + parts[1][r][j] + b2v;
            }
        }
    }
}

// ---- K-final: blocks 0..303 = DeCov (atomicAdd into out[8192]);
//      blocks 304..367 = final attention per batch ------------------------
__global__ __launch_bounds__(256) void k_final(
    const float* __restrict__ mha, const float* __restrict__ x,
    const float* __restrict__ feature_mask,
    const float* __restrict__ fWq, const float* __restrict__ fbq,
    const float* __restrict__ fWk, const float* __restrict__ fbk,
    const float* __restrict__ fWv, const float* __restrict__ fbv,
    const float* __restrict__ mask_scale, float* __restrict__ out)
{
    const int tid = threadIdx.x;

    if (blockIdx.x < NN*4) {
        // ---------------- DeCov partial for (n, d-chunk) ----------------
        __shared__ float Cs[BB][DD];     // 32 KB
        __shared__ float means[DD];
        __shared__ float reda[256];
        __shared__ float redb[256];
        const int n = blockIdx.x >> 2, dc = blockIdx.x & 3;
        for (int i = tid; i < BB*DD; i += 256) {
            const int bb = i / DD, d = i % DD;
            Cs[bb][d] = mha[((size_t)bb*NN + n)*DD + d];
        }
        __syncthreads();
        if (tid < DD) {
            float s = 0.f;
            for (int bb = 0; bb < BB; ++bb) s += Cs[bb][tid];
            means[tid] = s / (float)BB;
        }
        __syncthreads();
        if (tid < DD) {
            const float m = means[tid];
            for (int bb = 0; bb < BB; ++bb) Cs[bb][tid] -= m;
        }
        __syncthreads();
        float ss = 0.f, dd2 = 0.f;
        const float invB1 = 1.f/63.f;
        for (int qi = tid; qi < 1024; qi += 256) {
            const int d  = dc*32 + qi / 32;
            const int e4 = (qi % 32) * 4;
            float a0=0,a1=0,a2=0,a3=0;
            for (int bb = 0; bb < BB; ++bb) {
                const float cd = Cs[bb][d];
                const float4 ce = *(const float4*)&Cs[bb][e4];
                a0 += cd*ce.x; a1 += cd*ce.y; a2 += cd*ce.z; a3 += cd*ce.w;
            }
            a0*=invB1; a1*=invB1; a2*=invB1; a3*=invB1;
            ss += a0*a0+a1*a1+a2*a2+a3*a3;
            if (d >= e4 && d < e4+4) {
                const float c[4] = {a0,a1,a2,a3};
                const float cd = c[d-e4];
                dd2 += cd*cd;
            }
        }
        reda[tid] = ss; redb[tid] = dd2;
        __syncthreads();
        for (int s2 = 128; s2 >= 1; s2 >>= 1) {
            if (tid < s2) { reda[tid] += reda[tid+s2]; redb[tid] += redb[tid+s2]; }
            __syncthreads();
        }
        if (tid == 0) atomicAdd(&out[BB*FAH], 0.5f*(reda[0] - redb[0]));
        return;
    }

    // ---------------- Final attention for batch b ----------------
    __shared__ float Xs[NN][DD];   // 38 KB
    __shared__ float fqs[DD], gs[DD], ys[DD];
    __shared__ float es[NN];
    __shared__ float sc[2];
    const int b = blockIdx.x - NN*4;
    for (int i = tid; i < NN*DD; i += 256) {
        const int r = i / DD, d = i % DD;
        Xs[r][d] = x[((size_t)b*NN + r)*DD + d];
    }
    __syncthreads();
    if (tid < FAH) {   // fq = x[b, N-1] @ fWq + fbq
        float acc = 0.f;
        for (int d = 0; d < DD; ++d) acc += Xs[NN-1][d] * fWq[d*FAH + tid];
        fqs[tid] = acc + fbq[tid];
    }
    __syncthreads();
    if (tid < DD) {   // g = fWk @ fq
        float acc = 0.f;
        for (int a = 0; a < FAH; ++a) acc += fWk[tid*FAH + a] * fqs[a];
        gs[tid] = acc;
    }
    if (tid == 0) {   // c0 = fbk . fq
        float acc = 0.f;
        for (int a = 0; a < FAH; ++a) acc += fbk[a]*fqs[a];
        sc[0] = acc;
    }
    __syncthreads();
    const float msc = mask_scale[0];
    if (tid < NN) {   // fe[n] = x[n].g + c0 + msc*fm
        float acc = 0.f;
        for (int d = 0; d < DD; ++d) acc += Xs[tid][d]*gs[d];
        es[tid] = acc + sc[0] + msc * feature_mask[b*NN + tid];
    }
    __syncthreads();
    if (tid == 0) {
        float mx = -1e30f;
        for (int n2 = 0; n2 < NN; ++n2) mx = fmaxf(mx, es[n2]);
        float sum = 0.f;
        for (int n2 = 0; n2 < NN; ++n2) { const float e = expf(es[n2]-mx); es[n2] = e; sum += e; }
        sc[1] = 1.f/sum;
    }
    __syncthreads();
    if (tid < DD) {   // y = sum_n alpha[n] * x[n]
        const float inv = sc[1];
        float acc = 0.f;
        for (int n2 = 0; n2 < NN; ++n2) acc += es[n2]*Xs[n2][tid];
        ys[tid] = acc * inv;
    }
    __syncthreads();
    if (tid < FAH) {   // pooled = y @ fWv + fbv   (sum alpha = 1)
        float acc = 0.f;
        for (int d = 0; d < DD; ++d) acc += ys[d]*fWv[d*FAH + tid];
        out[(size_t)b*FAH + tid] = acc + fbv[tid];
    }
}

extern "C" void kernel_launch(void* const* d_in, const int* in_sizes, int n_in,
                              void* d_out, int out_size, void* d_ws, size_t ws_size,
                              hipStream_t stream) {
    const float* H    = (const float*)d_in[0];
    const float* mask = (const float*)d_in[1];
    const float* fm   = (const float*)d_in[2];
    const float* Wt   = (const float*)d_in[3];
    const float* Wx   = (const float*)d_in[4];
    const float* rate = (const float*)d_in[5];
    const float* obs_bias  = (const float*)d_in[6];
    const float* miss_bias = (const float*)d_in[7];
    const float* Wq = (const float*)d_in[8];   const float* bq = (const float*)d_in[9];
    const float* Wk = (const float*)d_in[10];  const float* bk = (const float*)d_in[11];
    const float* Wv = (const float*)d_in[12];  const float* bv = (const float*)d_in[13];
    const float* Wo = (const float*)d_in[14];  const float* bo = (const float*)d_in[15];
    const float* ln1a = (const float*)d_in[16]; const float* ln1b = (const float*)d_in[17];
    const float* ln2a = (const float*)d_in[18]; const float* ln2b = (const float*)d_in[19];
    const float* w1 = (const float*)d_in[20];  const float* b1 = (const float*)d_in[21];
    const float* w2 = (const float*)d_in[22];  const float* b2 = (const float*)d_in[23];
    const float* fWq = (const float*)d_in[24]; const float* fbq = (const float*)d_in[25];
    const float* fWk = (const float*)d_in[26]; const float* fbk = (const float*)d_in[27];
    const float* fWv = (const float*)d_in[28]; const float* fbv = (const float*)d_in[29];
    const float* mask_scale = (const float*)d_in[30];
    float* out = (float*)d_out;

    float* ws = (float*)d_ws;
    const size_t S = (size_t)BN*DD;   // 622592 floats
    float* emb = ws;
    float* qb  = ws + 1*S;
    float* kb  = ws + 2*S;
    float* vb  = ws + 3*S;
    float* ctx = ws + 4*S;
    float* mha = ws + 5*S;
    float* x2  = ws + 6*S;

    k1_temporal<<<BN, 512, 0, stream>>>(H, mask, Wt, Wx, rate, obs_bias, miss_bias, emb);
    k2a_ln_qkv<<<NBLK, 256, 0, stream>>>(emb, ln1a, ln1b, Wq, bq, Wk, bk, Wv, bv, qb, kb, vb);
    k2b_attn<<<BB*NHEADS, 128, 0, stream>>>(qb, kb, vb, ctx);
    k23_proj_ffn<<<NBLK, 256, 0, stream>>>(ctx, emb, Wo, bo, ln2a, ln2b, w1, b1, w2, b2, mha, x2, out);
    k_final<<<NN*4 + BB, 256, 0, stream>>>(mha, x2, fm, fWq, fbq, fWk, fbk, fWv, fbv, mask_scale, out);
}

// Round 12
// 180.835 us; speedup vs baseline: 1.5561x; 1.2456x over previous
//
#include <hip/hip_runtime.h>
#include <hip/hip_bf16.h>
#include <math.h>

#define BB 64
#define NN 76
#define TT 128
#define DD 128
#define AH 8
#define NHEADS 4
#define DFF 512
#define FAH 128
#define DK 32
#define BN (BB*NN)        // 4864
#define ROWS 8
#define NBLK (BN/ROWS)    // 608

// LDS-only barrier: waits ds ops (lgkmcnt) but leaves global register loads
// (vmcnt) in flight across the barrier. Avoids hipcc's __syncthreads lowering
// (s_waitcnt vmcnt(0) lgkmcnt(0)) which drains the in-flight tile stream.
__device__ __forceinline__ void bar_lds() {
    asm volatile("s_waitcnt lgkmcnt(0)" ::: "memory");
    __builtin_amdgcn_s_barrier();
    __builtin_amdgcn_sched_barrier(0);
}

// ---------------- K1: missing-aware temporal attention (best-known, R8) ---
// One-shot, 4864 blocks x 512 thr; H tile in registers (h[8]); weights staged
// in LDS; bounded-e softmax without max pass; 1/sum folded into emb store.
__global__ __launch_bounds__(512, 8) void k1_temporal(
    const float* __restrict__ H, const float* __restrict__ mask,
    const float* __restrict__ Wt, const float* __restrict__ Wx,
    const float* __restrict__ rate, const float* __restrict__ obs_bias,
    const float* __restrict__ miss_bias, float* __restrict__ emb)
{
    __shared__ __align__(16) float wtx[2*DD*AH];    // 8 KB: Wt then Wx
    __shared__ __align__(16) float wqs[DD];
    __shared__ __align__(16) float dots[TT];
    __shared__ __align__(16) float as_[TT];
    __shared__ __align__(16) float parts[16][DD];   // 8 KB
    __shared__ float qpart[2][AH];
    __shared__ float redsum[2];

    const int bid = blockIdx.x;   // b*N + n
    const int tid = threadIdx.x;
    const size_t base = (size_t)bid * (TT*DD);
    const int lane = tid & 63, w = tid >> 6;
    const int c = tid & 31, g = tid >> 5;

    // ---- oldest loads: weights chunk (1 float4/thread), r127, mask ----
    const float* wsrc = (tid < 256) ? (Wt + 4*tid) : (Wx + 4*(tid-256));
    const float4 wld = *(const float4*)wsrc;
    float r127 = 0.f, maskv = 0.f;
    if (tid < DD) {
        r127  = H[base + (TT-1)*DD + tid];
        maskv = mask[(size_t)bid*TT + tid];
    }
    const float sr   = 1.f / (1.f + expf(-rate[0]));
    const float obsv = obs_bias[0], missv = miss_bias[0];

    // ---- tile loads (youngest; stay in flight until the dot phase) ----
    float4 h[8];
    const float4* Hg4 = (const float4*)(H + base);
    #pragma unroll
    for (int j = 0; j < 8; ++j) h[j] = Hg4[j*512 + tid];

    // stage weights to LDS (waits only the oldest vmcnt entries)
    *(float4*)&wtx[4*tid] = wld;
    bar_lds();

    // q[a] = row127 . Wt[:,a]  (waves 0-1; Wt row from LDS)
    if (tid < DD) {
        float p[AH];
        #pragma unroll
        for (int a = 0; a < AH; ++a) p[a] = r127 * wtx[tid*AH + a];
        #pragma unroll
        for (int a = 0; a < AH; ++a) {
            float v = p[a];
            #pragma unroll
            for (int m = 1; m < 64; m <<= 1) v += __shfl_xor(v, m, 64);
            if (lane == 0) qpart[w][a] = v;
        }
    }
    bar_lds();
    // wq[d] = sum_a q[a]*Wx[d,a]  (Wx row from LDS)
    if (tid < DD) {
        float acc = 0.f;
        #pragma unroll
        for (int a = 0; a < AH; ++a)
            acc += (qpart[0][a] + qpart[1][a]) * wtx[DD*AH + tid*AH + a];
        wqs[tid] = acc;
    }
    bar_lds();

    // dot[t] = H[t] . wq ; rows t = g + 16j; 32-lane group reduce
    const float4 wq4 = *(const float4*)&wqs[4*c];
    #pragma unroll
    for (int j = 0; j < 8; ++j) {
        float p = h[j].x*wq4.x + h[j].y*wq4.y + h[j].z*wq4.z + h[j].w*wq4.w;
        #pragma unroll
        for (int m = 1; m < 32; m <<= 1) p += __shfl_xor(p, m, 64);
        if (c == 0) dots[g + 16*j] = p;
    }
    bar_lds();

    // e[t] + UNNORMALIZED exp (e bounded ~2.6 -> no max subtraction);
    // sum reduce only; 1/sum folded into the emb store.
    if (tid < TT) {
        const float dot = dots[tid];
        const float sig = 1.f / (1.f + expf(-dot));
        const float bt  = (float)(TT - tid);
        const float denom = sr * (logf(2.72f + (1.f - sig)) * bt);
        float e = fmaxf(sig / denom, 0.f);
        e += (maskv > 0.5f) ? obsv : missv;
        const float ex = expf(e);
        as_[tid] = ex;
        float vs = ex;
        #pragma unroll
        for (int m = 1; m < 64; m <<= 1) vs += __shfl_xor(vs, m, 64);
        if (lane == 0) redsum[w] = vs;
    }
    bar_lds();
    const float inv = 1.f / (redsum[0] + redsum[1]);

    // emb[d] = inv * sum_t ex[t]*H[t,d]  (register-local, 16-way combine)
    float4 facc = make_float4(0.f, 0.f, 0.f, 0.f);
    #pragma unroll
    for (int j = 0; j < 8; ++j) {
        const float a = as_[g + 16*j];
        facc.x += a*h[j].x; facc.y += a*h[j].y;
        facc.z += a*h[j].z; facc.w += a*h[j].w;
    }
    *(float4*)&parts[g][4*c] = facc;
    bar_lds();
    if (tid < DD) {
        float acc = 0.f;
        #pragma unroll
        for (int gg = 0; gg < 16; ++gg) acc += parts[gg][tid];
        emb[(size_t)bid*DD + tid] = acc * inv;
    }
}

// ---------------- K2a: LN1 + Q/K/V projections ----------------
__global__ __launch_bounds__(256) void k2a_ln_qkv(
    const float* __restrict__ emb,
    const float* __restrict__ ln_a, const float* __restrict__ ln_b,
    const float* __restrict__ Wq, const float* __restrict__ bq,
    const float* __restrict__ Wk, const float* __restrict__ bk,
    const float* __restrict__ Wv, const float* __restrict__ bv,
    float* __restrict__ qb, float* __restrict__ kb, float* __restrict__ vb)
{
    __shared__ float xs[ROWS][DD];
    const int tid = threadIdx.x;
    const int r0 = blockIdx.x * ROWS;

    for (int i = tid; i < ROWS*DD; i += 256) {
        const int r = i / DD, d = i % DD;
        xs[r][d] = emb[(size_t)(r0+r)*DD + d];
    }
    __syncthreads();

    {   // LayerNorm (ddof=1, eps added to std); wave w -> rows 2w,2w+1
        const int wv_ = tid >> 6, lane = tid & 63;
        for (int rr = 0; rr < 2; ++rr) {
            const int r = wv_*2 + rr;
            const float x0 = xs[r][lane], x1 = xs[r][lane+64];
            float s = x0 + x1;
            #pragma unroll
            for (int m = 1; m < 64; m <<= 1) s += __shfl_xor(s, m, 64);
            const float mean = s / (float)DD;
            const float d0 = x0 - mean, d1 = x1 - mean;
            float v = d0*d0 + d1*d1;
            #pragma unroll
            for (int m = 1; m < 64; m <<= 1) v += __shfl_xor(v, m, 64);
            const float inv = 1.f / (sqrtf(v / (float)(DD-1)) + 1e-7f);
            xs[r][lane]    = ln_a[lane]   * (d0*inv) + ln_b[lane];
            xs[r][lane+64] = ln_a[lane+64]* (d1*inv) + ln_b[lane+64];
        }
    }
    __syncthreads();

    const int j = tid & 127, half = tid >> 7, rbase = half*4;
    float aq[4] = {0,0,0,0}, ak[4] = {0,0,0,0}, av[4] = {0,0,0,0};
    for (int d = 0; d < DD; ++d) {
        const float wqv = Wq[d*DD+j], wkv = Wk[d*DD+j], wvv = Wv[d*DD+j];
        #pragma unroll
        for (int r = 0; r < 4; ++r) {
            const float xv = xs[rbase+r][d];
            aq[r] += xv*wqv; ak[r] += xv*wkv; av[r] += xv*wvv;
        }
    }
    const float bqv = bq[j], bkv = bk[j], bvv = bv[j];
    #pragma unroll
    for (int r = 0; r < 4; ++r) {
        const size_t o = (size_t)(r0 + rbase + r)*DD + j;
        qb[o] = aq[r]+bqv; kb[o] = ak[r]+bkv; vb[o] = av[r]+bvv;
    }
}

// ---------------- K2b: per-(b,head) self-attention over N ----------------
__global__ __launch_bounds__(128) void k2b_attn(
    const float* __restrict__ qb, const float* __restrict__ kb,
    const float* __restrict__ vb, float* __restrict__ ctx)
{
    __shared__ float Qs[NN][DK], Ks[NN][DK], Vs[NN][DK];
    __shared__ float Ps[NN][NN+1];   // stride 77: bank-conflict-free
    const int b = blockIdx.x / NHEADS, h = blockIdx.x % NHEADS;
    const int tid = threadIdx.x;
    const int co = h*DK;

    for (int i = tid; i < NN*DK; i += 128) {
        const int r = i / DK, c = i % DK;
        const size_t o = (size_t)(b*NN + r)*DD + co + c;
        Qs[r][c] = qb[o]; Ks[r][c] = kb[o]; Vs[r][c] = vb[o];
    }
    __syncthreads();

    const float scale = 0.17677669529663687f;   // 1/sqrt(32)
    if (tid < NN) {
        float qr[DK];
        #pragma unroll
        for (int c = 0; c < DK; ++c) qr[c] = Qs[tid][c];
        float mx = -1e30f;
        for (int k = 0; k < NN; ++k) {
            float s = 0.f;
            #pragma unroll
            for (int c = 0; c < DK; ++c) s += qr[c]*Ks[k][c];
            s *= scale;
            Ps[tid][k] = s;
            mx = fmaxf(mx, s);
        }
        float sum = 0.f;
        for (int k = 0; k < NN; ++k) { const float e = expf(Ps[tid][k]-mx); Ps[tid][k] = e; sum += e; }
        const float inv = 1.f/sum;
        float acc[DK];
        #pragma unroll
        for (int c = 0; c < DK; ++c) acc[c] = 0.f;
        for (int k = 0; k < NN; ++k) {
            const float p = Ps[tid][k];
            #pragma unroll
            for (int c = 0; c < DK; ++c) acc[c] += p*Vs[k][c];
        }
        const size_t o = (size_t)(b*NN + tid)*DD + co;
        #pragma unroll
        for (int c = 0; c < DK; ++c) ctx[o+c] = acc[c]*inv;
    }
}

// ---------------- K23: Wo projection + residual + LN2 + FFN + residual ----
__global__ __launch_bounds__(256) void k23_proj_ffn(
    const float* __restrict__ ctx, const float* __restrict__ emb,
    const float* __restrict__ Wo, const float* __restrict__ bo,
    const float* __restrict__ ln_a, const float* __restrict__ ln_b,
    const float* __restrict__ w1, const float* __restrict__ b1,
    const float* __restrict__ w2, const float* __restrict__ b2,
    float* __restrict__ mha, float* __restrict__ x2)
{
    __shared__ float cs[ROWS][DD];        // ctx rows
    __shared__ float xs[ROWS][DD];        // x = emb + mha
    __shared__ float x1s[ROWS][DD];       // LN2(x)
    __shared__ float hs[ROWS][DFF];       // 16 KB
    __shared__ float parts[2][ROWS][DD];  // 8 KB
    const int tid = threadIdx.x;
    const int r0 = blockIdx.x * ROWS;

    for (int i = tid; i < ROWS*DD; i += 256) {
        const int r = i / DD, d = i % DD;
        cs[r][d] = ctx[(size_t)(r0+r)*DD + d];
    }
    __syncthreads();

    {   // mha = ctx @ Wo + bo ; x = emb + mha (LDS); mha -> global
        const int j = tid & 127, half = tid >> 7, rbase = half*4;
        float acc[4] = {0,0,0,0};
        for (int d = 0; d < DD; ++d) {
            const float wv = Wo[d*DD+j];
            #pragma unroll
            for (int r = 0; r < 4; ++r) acc[r] += cs[rbase+r][d]*wv;
        }
        const float bov = bo[j];
        #pragma unroll
        for (int r = 0; r < 4; ++r) {
            const size_t o = (size_t)(r0+rbase+r)*DD + j;
            const float m = acc[r] + bov;
            mha[o] = m;
            xs[rbase+r][j] = emb[o] + m;
        }
    }
    __syncthreads();

    {   // LN2
        const int wv_ = tid >> 6, lane = tid & 63;
        for (int rr = 0; rr < 2; ++rr) {
            const int r = wv_*2 + rr;
            const float v0 = xs[r][lane], v1 = xs[r][lane+64];
            float s = v0 + v1;
            #pragma unroll
            for (int m = 1; m < 64; m <<= 1) s += __shfl_xor(s, m, 64);
            const float mean = s / (float)DD;
            const float d0 = v0-mean, d1 = v1-mean;
            float vv = d0*d0 + d1*d1;
            #pragma unroll
            for (int m = 1; m < 64; m <<= 1) vv += __shfl_xor(vv, m, 64);
            const float inv = 1.f / (sqrtf(vv/(float)(DD-1)) + 1e-7f);
            x1s[r][lane]    = ln_a[lane]   * (d0*inv) + ln_b[lane];
            x1s[r][lane+64] = ln_a[lane+64]* (d1*inv) + ln_b[lane+64];
        }
    }
    __syncthreads();

    {   // h = relu(x1 @ w1 + b1) ; thread -> cols tid, tid+256
        float acc0[ROWS], acc1[ROWS];
        #pragma unroll
        for (int r = 0; r < ROWS; ++r) { acc0[r]=0.f; acc1[r]=0.f; }
        for (int d = 0; d < DD; ++d) {
            const float wv0 = w1[d*DFF + tid], wv1 = w1[d*DFF + tid + 256];
            #pragma unroll
            for (int r = 0; r < ROWS; ++r) {
                const float xv = x1s[r][d];
                acc0[r] += xv*wv0; acc1[r] += xv*wv1;
            }
        }
        const float b10 = b1[tid], b11 = b1[tid+256];
        #pragma unroll
        for (int r = 0; r < ROWS; ++r) {
            hs[r][tid]     = fmaxf(acc0[r]+b10, 0.f);
            hs[r][tid+256] = fmaxf(acc1[r]+b11, 0.f);
        }
    }
    __syncthreads();

    {   // ffn = h @ w2 + b2 ; x2 = x + ffn
        const int j = tid & 127, half = tid >> 7;
        float acc[ROWS];
        #pragma unroll
        for (int r = 0; r < ROWS; ++r) acc[r] = 0.f;
        for (int k = half*256; k < half*256 + 256; ++k) {
            const float wv = w2[k*DD + j];
            #pragma unroll
            for (int r = 0; r < ROWS; ++r) acc[r] += hs[r][k]*wv;
        }
        #pragma unroll
        for (int r = 0; r < ROWS; ++r) parts[half][r][j] = acc[r];
        __syncthreads();
        if (half == 0) {
            const float b2v = b2[j];
            #pragma unroll
            for (int r = 0; r < ROWS; ++r) {
                const size_t o = (size_t)(r0+r)*DD + j;
                x2[o] = xs[r][j] + parts[0][r][j] + parts[1][r][j] + b2v;
            }
        }
    }
}

// ---------------- K-decov: DeCov partials per (n, d-chunk) ----------------
__global__ __launch_bounds__(256) void k_decov(
    const float* __restrict__ mha, float* __restrict__ partial)
{
    __shared__ float Cs[BB][DD];     // 32 KB
    __shared__ float means[DD];
    __shared__ float reda[256];
    __shared__ float redb[256];
    const int n = blockIdx.x, dc = blockIdx.y;
    const int tid = threadIdx.x;
    for (int i = tid; i < BB*DD; i += 256) {
        const int bb = i / DD, d = i % DD;
        Cs[bb][d] = mha[((size_t)bb*NN + n)*DD + d];
    }
    __syncthreads();
    if (tid < DD) {
        float s = 0.f;
        for (int bb = 0; bb < BB; ++bb) s += Cs[bb][tid];
        means[tid] = s / (float)BB;
    }
    __syncthreads();
    if (tid < DD) {
        const float m = means[tid];
        for (int bb = 0; bb < BB; ++bb) Cs[bb][tid] -= m;
    }
    __syncthreads();
    float ss = 0.f, dd2 = 0.f;
    const float invB1 = 1.f/63.f;
    for (int qi = tid; qi < 1024; qi += 256) {
        const int d  = dc*32 + qi / 32;
        const int e4 = (qi % 32) * 4;
        float a0=0,a1=0,a2=0,a3=0;
        for (int bb = 0; bb < BB; ++bb) {
            const float cd = Cs[bb][d];
            const float4 ce = *(const float4*)&Cs[bb][e4];
            a0 += cd*ce.x; a1 += cd*ce.y; a2 += cd*ce.z; a3 += cd*ce.w;
        }
        a0*=invB1; a1*=invB1; a2*=invB1; a3*=invB1;
        ss += a0*a0+a1*a1+a2*a2+a3*a3;
        if (d >= e4 && d < e4+4) {
            const float c[4] = {a0,a1,a2,a3};
            const float cd = c[d-e4];
            dd2 += cd*cd;
        }
    }
    reda[tid] = ss; redb[tid] = dd2;
    __syncthreads();
    for (int s2 = 128; s2 >= 1; s2 >>= 1) {
        if (tid < s2) { reda[tid] += reda[tid+s2]; redb[tid] += redb[tid+s2]; }
        __syncthreads();
    }
    if (tid == 0) partial[n*4 + dc] = 0.5f*(reda[0] - redb[0]);
}

// ---------------- K4: final attention + decov sum ----------------
__global__ __launch_bounds__(128) void k4_final(
    const float* __restrict__ x, const float* __restrict__ feature_mask,
    const float* __restrict__ fWq, const float* __restrict__ fbq,
    const float* __restrict__ fWk, const float* __restrict__ fbk,
    const float* __restrict__ fWv, const float* __restrict__ fbv,
    const float* __restrict__ mask_scale, const float* __restrict__ decov_partial,
    float* __restrict__ out)
{
    __shared__ float Xs[NN][DD];   // 38 KB
    __shared__ float fqs[DD], gs[DD], ys[DD];
    __shared__ float es[NN];
    __shared__ float sc[2];
    const int b = blockIdx.x;
    const int tid = threadIdx.x;
    for (int i = tid; i < NN*DD; i += 128) {
        const int r = i / DD, d = i % DD;
        Xs[r][d] = x[((size_t)b*NN + r)*DD + d];
    }
    __syncthreads();
    {   // fq = x[b, N-1] @ fWq + fbq
        float acc = 0.f;
        for (int d = 0; d < DD; ++d) acc += Xs[NN-1][d] * fWq[d*FAH + tid];
        fqs[tid] = acc + fbq[tid];
    }
    __syncthreads();
    {   // g = fWk @ fq ; c0 = fbk . fq
        float acc = 0.f;
        for (int a = 0; a < FAH; ++a) acc += fWk[tid*FAH + a] * fqs[a];
        gs[tid] = acc;
    }
    if (tid == 0) {
        float acc = 0.f;
        for (int a = 0; a < FAH; ++a) acc += fbk[a]*fqs[a];
        sc[0] = acc;
    }
    __syncthreads();
    const float msc = mask_scale[0];
    if (tid < NN) {   // fe[n] = x[n].g + c0 + msc*fm
        float acc = 0.f;
        for (int d = 0; d < DD; ++d) acc += Xs[tid][d]*gs[d];
        es[tid] = acc + sc[0] + msc * feature_mask[b*NN + tid];
    }
    __syncthreads();
    if (tid == 0) {
        float mx = -1e30f;
        for (int n2 = 0; n2 < NN; ++n2) mx = fmaxf(mx, es[n2]);
        float sum = 0.f;
        for (int n2 = 0; n2 < NN; ++n2) { const float e = expf(es[n2]-mx); es[n2] = e; sum += e; }
        sc[1] = 1.f/sum;
    }
    __syncthreads();
    {   // y = sum_n alpha[n] * x[n]
        const float inv = sc[1];
        float acc = 0.f;
        for (int n2 = 0; n2 < NN; ++n2) acc += es[n2]*Xs[n2][tid];
        ys[tid] = acc * inv;
    }
    __syncthreads();
    {   // pooled = y @ fWv + fbv   (valid since sum alpha = 1)
        float acc = 0.f;
        for (int d = 0; d < DD; ++d) acc += ys[d]*fWv[d*FAH + tid];
        out[(size_t)b*FAH + tid] = acc + fbv[tid];
    }
    if (b == 0 && tid == 0) {
        float s = 0.f;
        for (int i = 0; i < NN*4; ++i) s += decov_partial[i];
        out[BB*FAH] = s;
    }
}

extern "C" void kernel_launch(void* const* d_in, const int* in_sizes, int n_in,
                              void* d_out, int out_size, void* d_ws, size_t ws_size,
                              hipStream_t stream) {
    const float* H    = (const float*)d_in[0];
    const float* mask = (const float*)d_in[1];
    const float* fm   = (const float*)d_in[2];
    const float* Wt   = (const float*)d_in[3];
    const float* Wx   = (const float*)d_in[4];
    const float* rate = (const float*)d_in[5];
    const float* obs_bias  = (const float*)d_in[6];
    const float* miss_bias = (const float*)d_in[7];
    const float* Wq = (const float*)d_in[8];   const float* bq = (const float*)d_in[9];
    const float* Wk = (const float*)d_in[10];  const float* bk = (const float*)d_in[11];
    const float* Wv = (const float*)d_in[12];  const float* bv = (const float*)d_in[13];
    const float* Wo = (const float*)d_in[14];  const float* bo = (const float*)d_in[15];
    const float* ln1a = (const float*)d_in[16]; const float* ln1b = (const float*)d_in[17];
    const float* ln2a = (const float*)d_in[18]; const float* ln2b = (const float*)d_in[19];
    const float* w1 = (const float*)d_in[20];  const float* b1 = (const float*)d_in[21];
    const float* w2 = (const float*)d_in[22];  const float* b2 = (const float*)d_in[23];
    const float* fWq = (const float*)d_in[24]; const float* fbq = (const float*)d_in[25];
    const float* fWk = (const float*)d_in[26]; const float* fbk = (const float*)d_in[27];
    const float* fWv = (const float*)d_in[28]; const float* fbv = (const float*)d_in[29];
    const float* mask_scale = (const float*)d_in[30];
    float* out = (float*)d_out;

    float* ws = (float*)d_ws;
    const size_t S = (size_t)BN*DD;   // 622592 floats
    float* emb = ws;
    float* qb  = ws + 1*S;
    float* kb  = ws + 2*S;
    float* vb  = ws + 3*S;
    float* ctx = ws + 4*S;
    float* mha = ws + 5*S;
    float* x2  = ws + 6*S;
    float* dpart = ws + 7*S;          // 304 floats

    k1_temporal<<<BN, 512, 0, stream>>>(H, mask, Wt, Wx, rate, obs_bias, miss_bias, emb);
    k2a_ln_qkv<<<NBLK, 256, 0, stream>>>(emb, ln1a, ln1b, Wq, bq, Wk, bk, Wv, bv, qb, kb, vb);
    k2b_attn<<<BB*NHEADS, 128, 0, stream>>>(qb, kb, vb, ctx);
    k23_proj_ffn<<<NBLK, 256, 0, stream>>>(ctx, emb, Wo, bo, ln2a, ln2b, w1, b1, w2, b2, mha, x2);
    k_decov<<<dim3(NN, 4), 256, 0, stream>>>(mha, dpart);
    k4_final<<<BB, 128, 0, stream>>>(x2, fm, fWq, fbq, fWk, fbk, fWv, fbv, mask_scale, dpart, out);
}